// Round 10
// baseline (242.836 us; speedup 1.0000x reference)
//
#include <hip/hip_runtime.h>

typedef unsigned short ushort_t;

#define NVOX 4096
#define NSV  256
#define XD   128
#define YD   128
#define ZD   16
#define CD   128
#define NCD  20
#define HD   8
#define DHD  16
#define MAPN 524288
#define EPSF 1e-5f

// ---- fp32 arena offsets (floats) ----
#define OF_FEAT 0
#define OF_CW1  524288
#define OF_CB1  540672
#define OF_CG1  540800
#define OF_CBE1 540928
#define OF_CW2  541056
#define OF_CB2  557440
#define OF_PW1  557568
#define OF_PB1  557760
#define OF_PG1  557824
#define OF_PBE1 557888
#define OF_PW2  557952
#define OF_PB2  558016
#define OF_WQ   558080
#define OF_BQ   574464
#define OF_WK   574592
#define OF_BK   590976
#define OF_WV   591104
#define OF_BV   607488
#define OF_WO   607616
#define OF_BO   624000
#define OF_LNG  624128
#define OF_LNB  624256
#define OF_SEGW 624384
#define OF_SEGB 693504
#define ARENA_N 693568
#define TOTCVT  624341   /* segw excluded (transposed separately) */

__device__ __forceinline__ float bf2f(const ushort_t* p){
  return __uint_as_float(((unsigned)(*p)) << 16);
}
__device__ __forceinline__ ushort_t f2bf(float f){
  unsigned u = __float_as_uint(f);
  u += 0x7fffu + ((u >> 16) & 1u);
  return (ushort_t)(u >> 16);
}
__device__ __forceinline__ float unlo(unsigned u){ return __uint_as_float(u << 16); }
__device__ __forceinline__ float unhi(unsigned u){ return __uint_as_float(u & 0xffff0000u); }

struct SrcPtrs { const void* p[25]; };

__device__ const int g_cnt[25] = {524288,16384,128,128,128,16384,128,192,64,64,64,64,1,
                                  16384,128,16384,128,16384,128,16384,128,128,128,0,20};
__device__ const int g_off[25] = {OF_FEAT,OF_CW1,OF_CB1,OF_CG1,OF_CBE1,OF_CW2,OF_CB2,
                                  OF_PW1,OF_PB1,OF_PG1,OF_PBE1,OF_PW2,OF_PB2,
                                  OF_WQ,OF_BQ,OF_WK,OF_BK,OF_WV,OF_BV,OF_WO,OF_BO,
                                  OF_LNG,OF_LNB,OF_SEGW,OF_SEGB};

__device__ __forceinline__ float ldi(const void* p, int off, int fl){
  return fl ? bf2f((const ushort_t*)p + off) : ((const float*)p)[off];
}

struct SPREP {
  float frows[16][CD];     // 8 KB
  float qpart[2][16][CD];  // 16 KB
  float part[8][CD];       // 4 KB
  float cfs[CD];           // 0.5 KB
  float gpart[8][CD];      // 4 KB
};
union __align__(16) UPREP { SPREP sv; int smom[18]; };

// ========== KPREP (512 threads) ==========
__global__ __launch_bounds__(512) void kprep(SrcPtrs sp, const int* idx, int* flag,
    float* arena, float* wt, int* map, float* afold_g, float* scfold_g,
    float* qb, float* t1T)
{
  __shared__ UPREP sm;
  __shared__ int sm_flag;
  int t = threadIdx.x, b = blockIdx.x;
  if (t < 64){
    const ushort_t* f16 = (const ushort_t*)sp.p[0];
    unsigned u = f16[2*t];
    int e = (u >> 7) & 0xFF;
    int sane = (u == 0 || (e >= 90 && e <= 150)) ? 1 : 0;
    unsigned long long bl = __ballot(sane);
    if (t == 0) sm_flag = (__popcll(bl) >= 48) ? 1 : 0;
  }
  __syncthreads();
  const int fl = sm_flag;

  if (b < 255){
    int gid = b*512 + t;
    const int GS = 255*512;
    if (gid == 0) *flag = fl;
    for (int k=gid; k<MAPN; k+=GS) map[k] = -1;
    for (int el=gid; el<TOTCVT; el+=GS){
      int s=0, rem=el;
      while (rem >= g_cnt[s]){ rem -= g_cnt[s]; ++s; }
      arena[g_off[s]+rem] = ldi(sp.p[s], rem, fl);
    }
    for (int k=gid; k<27*NCD*CD; k+=GS){
      int nb = k/(NCD*CD); int rem = k - nb*(NCD*CD); int o = rem/CD, i = rem - o*CD;
      wt[k] = ldi(sp.p[23], nb*(CD*NCD) + i*NCD + o, fl);
    }
  } else if (b < 511){
    int sv = b - 255;
    int rb = sv*16;
    if (fl){
      const uint2* fsrc = (const uint2*)((const ushort_t*)sp.p[0] + (size_t)rb*CD);
      uint2 u = fsrc[t];
      float* dst = &sm.sv.frows[t>>5][(t&31)*4];
      dst[0]=unlo(u.x); dst[1]=unhi(u.x); dst[2]=unlo(u.y); dst[3]=unhi(u.y);
    } else {
      const float4* fsrc = (const float4*)((const float*)sp.p[0] + (size_t)rb*CD);
      ((float4*)sm.sv.frows)[t] = fsrc[t];
    }
    __syncthreads();
    // ---- q-proj: thread = (c8:16, row:16, khalf:2)
    {
      int c8 = (t&15)*8, r = (t>>4)&15, kh = t>>8;
      int i0 = kh*64;
      float acc[8] = {0.f,0.f,0.f,0.f,0.f,0.f,0.f,0.f};
      if (fl){
        const ushort_t* wqp = (const ushort_t*)sp.p[13];
        #pragma unroll 4
        for (int i=i0; i<i0+64; ++i){
          uint4 w4 = *(const uint4*)(wqp + (size_t)i*CD + c8);
          float fr = sm.sv.frows[r][i];
          acc[0] += unlo(w4.x)*fr; acc[1] += unhi(w4.x)*fr;
          acc[2] += unlo(w4.y)*fr; acc[3] += unhi(w4.y)*fr;
          acc[4] += unlo(w4.z)*fr; acc[5] += unhi(w4.z)*fr;
          acc[6] += unlo(w4.w)*fr; acc[7] += unhi(w4.w)*fr;
        }
      } else {
        const float* wqp = (const float*)sp.p[13];
        #pragma unroll 4
        for (int i=i0; i<i0+64; ++i){
          float4 wa = *(const float4*)(wqp + (size_t)i*CD + c8);
          float4 wb = *(const float4*)(wqp + (size_t)i*CD + c8 + 4);
          float fr = sm.sv.frows[r][i];
          acc[0]+=wa.x*fr; acc[1]+=wa.y*fr; acc[2]+=wa.z*fr; acc[3]+=wa.w*fr;
          acc[4]+=wb.x*fr; acc[5]+=wb.y*fr; acc[6]+=wb.z*fr; acc[7]+=wb.w*fr;
        }
      }
      #pragma unroll
      for (int j=0;j<8;++j) sm.sv.qpart[kh][r][c8+j] = acc[j];
    }
    __syncthreads();
    for (int e = t; e < 16*CD; e += 512){
      int r = e>>7, c = e&127;
      qb[(size_t)(rb+r)*CD + c] = sm.sv.qpart[0][r][c] + sm.sv.qpart[1][r][c]
                                + ldi(sp.p[14], c, fl);
    }
    // ---- segment softmax-sum: 8 waves x 2 rows
    {
      int w = t>>6, l = t&63;
      float a0 = 0.f, a1 = 0.f;
      #pragma unroll
      for (int k=0;k<2;++k){
        int r = w*2 + k;
        float f0 = sm.sv.frows[r][l];
        float f1 = sm.sv.frows[r][l+64];
        float m = fmaxf(f0,f1);
        #pragma unroll
        for (int o=32;o;o>>=1) m = fmaxf(m, __shfl_xor(m,o,64));
        float e0 = __expf(f0-m), e1 = __expf(f1-m);
        float ssum = e0+e1;
        #pragma unroll
        for (int o=32;o;o>>=1) ssum += __shfl_xor(ssum,o,64);
        float inv = 1.f/ssum;
        a0 += e0*inv; a1 += e1*inv;
      }
      sm.sv.part[w][l] = a0; sm.sv.part[w][l+64] = a1;
    }
    __syncthreads();
    if (t < CD){
      float s = 0.f;
      #pragma unroll
      for (int w=0;w<8;++w) s += sm.sv.part[w][t];
      sm.sv.cfs[t] = s;
    }
    __syncthreads();
    // ---- GEMV1: thread = (c2:64, kg:8)
    {
      int c2 = (t&63)*2, kg = t>>6;
      int i0 = kg*16;
      float a0 = 0.f, a1 = 0.f;
      if (fl){
        const ushort_t* W = (const ushort_t*)sp.p[1];
        #pragma unroll 4
        for (int i=i0; i<i0+16; ++i){
          unsigned w = *(const unsigned*)(W + (size_t)i*CD + c2);
          float cfv = sm.sv.cfs[i];
          a0 += unlo(w)*cfv; a1 += unhi(w)*cfv;
        }
      } else {
        const float* W = (const float*)sp.p[1];
        #pragma unroll 4
        for (int i=i0; i<i0+16; ++i){
          float2 w = *(const float2*)(W + (size_t)i*CD + c2);
          float cfv = sm.sv.cfs[i];
          a0 += w.x*cfv; a1 += w.y*cfv;
        }
      }
      sm.sv.gpart[kg][c2] = a0; sm.sv.gpart[kg][c2+1] = a1;
    }
    __syncthreads();
    if (t < CD){
      float s = 0.f;
      #pragma unroll
      for (int kg=0;kg<8;++kg) s += sm.sv.gpart[kg][t];
      t1T[(size_t)t*NSV + sv] = s + ldi(sp.p[2], t, fl);
    }
  } else {
    // ---- b == 511: moments + BN fold
    if (t < 18) sm.smom[t] = 0;
    __syncthreads();
    int sacc[9] = {0,0,0,0,0,0,0,0,0};
    for (int v = t; v < NVOX; v += 512){
      int4 q = ((const int4*)idx)[v];
      sacc[0]+=q.y; sacc[1]+=q.z; sacc[2]+=q.w;
      sacc[3]+=q.y*q.y; sacc[4]+=q.z*q.z; sacc[5]+=q.w*q.w;
      sacc[6]+=q.y*q.z; sacc[7]+=q.y*q.w; sacc[8]+=q.z*q.w;
    }
    for (int i=0;i<9;++i) atomicAdd(&sm.smom[9+i], sacc[i]);
    if (t < 256){
      int4 q = ((const int4*)idx)[t*16];
      int gx=q.y>>2, gy=q.z>>2, gz=q.w>>2;
      atomicAdd(&sm.smom[0], gx); atomicAdd(&sm.smom[1], gy); atomicAdd(&sm.smom[2], gz);
      atomicAdd(&sm.smom[3], gx*gx); atomicAdd(&sm.smom[4], gy*gy); atomicAdd(&sm.smom[5], gz*gz);
      atomicAdd(&sm.smom[6], gx*gy); atomicAdd(&sm.smom[7], gx*gz); atomicAdd(&sm.smom[8], gy*gz);
    }
    __syncthreads();
    if (t < 64){
      int* smom = sm.smom;
      double U1[3]={(double)smom[0],(double)smom[1],(double)smom[2]};
      double S1[3]={(double)smom[9],(double)smom[10],(double)smom[11]};
      double Uxx[3][3], Sxx[3][3];
      Uxx[0][0]=smom[3]; Uxx[1][1]=smom[4]; Uxx[2][2]=smom[5];
      Uxx[0][1]=Uxx[1][0]=smom[6]; Uxx[0][2]=Uxx[2][0]=smom[7]; Uxx[1][2]=Uxx[2][1]=smom[8];
      Sxx[0][0]=smom[12]; Sxx[1][1]=smom[13]; Sxx[2][2]=smom[14];
      Sxx[0][1]=Sxx[1][0]=smom[15]; Sxx[0][2]=Sxx[2][0]=smom[16]; Sxx[1][2]=Sxx[2][1]=smom[17];
      double M1[3], M2[3][3];
      for (int a=0;a<3;++a) M1[a] = 256.0*S1[a] - 4096.0*U1[a];
      for (int a=0;a<3;++a)
        for (int b2=0;b2<3;++b2)
          M2[a][b2] = 256.0*Sxx[a][b2] - S1[a]*U1[b2] - S1[b2]*U1[a] + 4096.0*Uxx[a][b2];
      double wv_[3]={(double)ldi(sp.p[7],t,fl),(double)ldi(sp.p[7],64+t,fl),(double)ldi(sp.p[7],128+t,fl)};
      double bj=(double)ldi(sp.p[8],t,fl), gj=(double)ldi(sp.p[9],t,fl), bej=(double)ldi(sp.p[10],t,fl);
      double Mw=0.0, wMw=0.0;
      for (int a=0;a<3;++a){
        Mw += M1[a]*wv_[a];
        for (int b2=0;b2<3;++b2) wMw += wv_[a]*M2[a][b2]*wv_[b2];
      }
      const double NM = 1048576.0;
      double mean = Mw/NM + bj;
      double Ey2  = wMw/NM + 2.0*bj*Mw/NM + bj*bj;
      double var  = Ey2 - mean*mean;
      double scale = gj / sqrt(var + 1e-5);
      afold_g[t]      = (float)(wv_[0]*scale);
      afold_g[64+t]   = (float)(wv_[1]*scale);
      afold_g[128+t]  = (float)(wv_[2]*scale);
      scfold_g[t]     = (float)(bj*scale + bej - mean*scale);
    }
  }
}

// ========== K6: 512 blocks (role = b>>8: 0=k, 1=v); map scatter on role 0 ==========
__global__ __launch_bounds__(256) void k6_fused(const float* t1T, const float* A,
    const int* idx, int* map, float* kb, float* vb){
  __shared__ float row[CD];
  __shared__ float cpar[2][CD];
  __shared__ float hrow[CD];
  int t = threadIdx.x;
  int role = blockIdx.x >> 8, s = blockIdx.x & 255;
  if (role == 0 && t >= 128 && t < 144){
    int v = s*16 + (t-128);
    int4 q = ((const int4*)idx)[v];
    map[((q.x*XD + q.y)*YD + q.z)*ZD + q.w] = v;
  }
  if (t < CD){
    const float4* col = (const float4*)(t1T + (size_t)t*NSV);
    float sum=0.f, sq=0.f;
    #pragma unroll 8
    for (int i=0;i<NSV/4;++i){
      float4 v = col[i];
      sum += v.x+v.y+v.z+v.w;
      sq  += v.x*v.x+v.y*v.y+v.z*v.z+v.w*v.w;
    }
    float mean = sum*(1.f/256.f);
    float var  = sq*(1.f/256.f) - mean*mean;
    float scv = A[OF_CG1+t]*rsqrtf(var+EPSF);
    float shv = A[OF_CBE1+t] - mean*scv;
    row[t] = fmaxf(t1T[(size_t)t*NSV + s]*scv + shv, 0.f);
  }
  __syncthreads();
  int c = t&127, half = t>>7;
  {
    const float* W = A + OF_CW2;
    float acc = 0.f;
    #pragma unroll 8
    for (int i=half*64;i<half*64+64;++i) acc += row[i]*W[i*CD+c];
    cpar[half][c] = acc;
  }
  __syncthreads();
  if (t < CD) hrow[t] = cpar[0][t]+cpar[1][t]+A[OF_CB2+t];
  __syncthreads();
  // proj: split K over thread halves
  {
    const float* W = role ? (A+OF_WV) : (A+OF_WK);
    float acc = 0.f;
    #pragma unroll 8
    for (int i=half*64;i<half*64+64;++i) acc += hrow[i]*W[i*CD+c];
    cpar[half][c] = acc;
  }
  __syncthreads();
  if (t < CD){
    float v = cpar[0][t]+cpar[1][t] + (role ? A[OF_BV+t] : A[OF_BK+t]);
    if (role) vb[(size_t)s*CD+t] = v; else kb[(size_t)s*CD+t] = v;
  }
}

// ========== K9: pbias + attention + wo + residual + LN (4q/block, fp32 probs)
__global__ __launch_bounds__(256) void k9_attn(
    const float* A, const int* idx, const float* afold_g, const float* scfold_g,
    const float* kb, const float* vb, const float* qb, float* yb)
{
  __shared__ __align__(16) float q4s[4][CD];       // 2 KB
  __shared__ __align__(16) float scf[NSV][36];     // 36.9 KB fp32 probs [s][h*4+g]
  __shared__ __align__(16) float ctxT[CD*4];       // 2 KB
  __shared__ float cpart[2][4][CD];                // 4 KB
  __shared__ __align__(16) float e4T[64][4];       // 1 KB
  __shared__ float saf[3][64];
  __shared__ float ssc[64];
  __shared__ float w2s[64];
  __shared__ float rinv[32];
  int t = threadIdx.x;
  int n0 = blockIdx.x*4;
  if (t < 128) ((float4*)q4s)[t] = ((const float4*)(qb + (size_t)n0*CD))[t];
  if (t < 64){
    saf[0][t] = afold_g[t]; saf[1][t] = afold_g[64+t]; saf[2][t] = afold_g[128+t];
    ssc[t] = scfold_g[t]; w2s[t] = A[OF_PW2+t];
  }
  __syncthreads();
  {
    int g = t>>6, j = t&63;
    float xv = (float)idx[4*(n0+g)+1];
    float yv = (float)idx[4*(n0+g)+2];
    float zv = (float)idx[4*(n0+g)+3];
    e4T[j][g] = saf[0][j]*xv + saf[1][j]*yv + saf[2][j]*zv;
  }
  __syncthreads();
  // pbias + scores + exp for supervoxel s = t
  {
    int4 q0 = ((const int4*)idx)[t*16];
    float uxf = (float)(q0.y>>2), uyf = (float)(q0.z>>2), uzf = (float)(q0.w>>2);
    float pbv[4];
    float pb2v = A[OF_PB2];
    #pragma unroll
    for (int g=0;g<4;++g) pbv[g] = pb2v;
    #pragma unroll 2
    for (int j=0;j<64;++j){
      float dj = ssc[j] - (saf[0][j]*uxf + saf[1][j]*uyf + saf[2][j]*uzf);
      float wj = w2s[j];
      float4 ea = *(const float4*)&e4T[j][0];
      pbv[0] += fmaxf(ea.x+dj,0.f)*wj; pbv[1] += fmaxf(ea.y+dj,0.f)*wj;
      pbv[2] += fmaxf(ea.z+dj,0.f)*wj; pbv[3] += fmaxf(ea.w+dj,0.f)*wj;
    }
    const float4* krow = (const float4*)(kb + (size_t)t*CD);
    float4 kc0 = krow[0], kc1 = krow[1], kc2 = krow[2], kc3 = krow[3];
    for (int h=0;h<HD;++h){
      int hn = (h+1)&7;
      float4 kn0 = krow[hn*4+0], kn1 = krow[hn*4+1];
      float4 kn2 = krow[hn*4+2], kn3 = krow[hn*4+3];
      float p[4];
      #pragma unroll
      for (int g=0;g<4;++g){
        const float* qg = &q4s[g][h*DHD];
        float dot = qg[0]*kc0.x + qg[1]*kc0.y + qg[2]*kc0.z + qg[3]*kc0.w
                  + qg[4]*kc1.x + qg[5]*kc1.y + qg[6]*kc1.z + qg[7]*kc1.w
                  + qg[8]*kc2.x + qg[9]*kc2.y + qg[10]*kc2.z + qg[11]*kc2.w
                  + qg[12]*kc3.x + qg[13]*kc3.y + qg[14]*kc3.z + qg[15]*kc3.w;
        p[g] = __expf(dot*0.25f + pbv[g]);
      }
      *(float4*)&scf[t][h*4] = make_float4(p[0],p[1],p[2],p[3]);
      kc0 = kn0; kc1 = kn1; kc2 = kn2; kc3 = kn3;
    }
  }
  __syncthreads();
  // denominators: wave g handles query g, all 8 heads
  {
    int g = t>>6, lane = t&63;
    for (int h=0;h<HD;++h){
      int col = h*4 + g;
      float s0 = scf[lane][col] + scf[lane+64][col] + scf[lane+128][col] + scf[lane+192][col];
      #pragma unroll
      for (int o=32;o;o>>=1) s0 += __shfl_xor(s0,o,64);
      if (lane==0) rinv[g*8+h] = 1.f/s0;
    }
  }
  __syncthreads();
  // PV: float4 LDS broadcast + 4-wide v-load unroll
  {
    int half=t>>7, c=t&127, h=c>>4;
    const float* vcol = vb + c;
    float acc[4]={0.f,0.f,0.f,0.f};
    #pragma unroll 4
    for (int s0=half*128; s0<half*128+128; s0+=4){
      float v0=vcol[(s0+0)*CD], v1=vcol[(s0+1)*CD], v2=vcol[(s0+2)*CD], v3=vcol[(s0+3)*CD];
      float4 p0 = *(const float4*)&scf[s0+0][h*4];
      float4 p1 = *(const float4*)&scf[s0+1][h*4];
      float4 p2 = *(const float4*)&scf[s0+2][h*4];
      float4 p3 = *(const float4*)&scf[s0+3][h*4];
      acc[0] += p0.x*v0 + p1.x*v1 + p2.x*v2 + p3.x*v3;
      acc[1] += p0.y*v0 + p1.y*v1 + p2.y*v2 + p3.y*v3;
      acc[2] += p0.z*v0 + p1.z*v1 + p2.z*v2 + p3.z*v3;
      acc[3] += p0.w*v0 + p1.w*v1 + p2.w*v2 + p3.w*v3;
    }
    #pragma unroll
    for (int g=0;g<4;++g) cpart[half][g][c]=acc[g];
  }
  __syncthreads();
  if (t < CD){
    int h = t>>4;
    #pragma unroll
    for (int g=0;g<4;++g)
      ctxT[t*4+g] = (cpart[0][g][t]+cpart[1][g][t])*rinv[g*8+h];
  }
  __syncthreads();
  // wo
  {
    int half=t>>7, c=t&127;
    const float* wo = A + OF_WO;
    float acc[4]={0.f,0.f,0.f,0.f};
    #pragma unroll 4
    for (int i=half*64;i<half*64+64;++i){
      float wv = wo[i*CD+c];
      float4 r = *(const float4*)&ctxT[i*4];
      acc[0]+=r.x*wv; acc[1]+=r.y*wv; acc[2]+=r.z*wv; acc[3]+=r.w*wv;
    }
    #pragma unroll
    for (int g=0;g<4;++g) cpart[half][g][c]=acc[g];
  }
  __syncthreads();
  if (t < CD){
    float bov = A[OF_BO+t];
    #pragma unroll
    for (int g=0;g<4;++g)
      ctxT[t*4+g] = cpart[0][g][t]+cpart[1][g][t] + bov
                  + A[OF_FEAT + (size_t)(n0+g)*CD + t];
  }
  __syncthreads();
  // LayerNorm: wave g handles row g
  {
    int g = t>>6, lane = t&63;
    float x0 = ctxT[lane*4+g], x1 = ctxT[(lane+64)*4+g];
    float s1 = x0+x1, s2 = x0*x0+x1*x1;
    #pragma unroll
    for (int o=32;o;o>>=1){ s1 += __shfl_xor(s1,o,64); s2 += __shfl_xor(s2,o,64); }
    float mean = s1*(1.f/128.f);
    float var  = s2*(1.f/128.f) - mean*mean;
    float rs = rsqrtf(var + EPSF);
    yb[(size_t)(n0+g)*CD + lane]    = (x0-mean)*rs*A[OF_LNG+lane]    + A[OF_LNB+lane];
    yb[(size_t)(n0+g)*CD + lane+64] = (x1-mean)*rs*A[OF_LNG+lane+64] + A[OF_LNB+lane+64];
  }
}

// ========== K10: SubMConv3d, 8 voxels/block (512 blocks), weights hoisted ==========
__global__ __launch_bounds__(256) void k10_conv(const int* idx, const int* map,
    const float* yb, const float* A, const float* wt, const int* flag, void* outv)
{
  __shared__ int sco4[8][4];
  __shared__ int jn[8][27];
  __shared__ float partial[4][8][NCD];
  int t = threadIdx.x;
  int p0 = blockIdx.x*8;
  if (t < 32) ((int*)sco4)[t] = idx[4*p0 + t];
  __syncthreads();
  if (t < 216){
    int v = t/27, nb = t - v*27;
    int kd = nb/9, kh = (nb/3)%3, kw = nb%3;
    int bb = sco4[v][0];
    int nx = sco4[v][1]+kd-1, ny = sco4[v][2]+kh-1, nz = sco4[v][3]+kw-1;
    int j = -1;
    if ((unsigned)nx < XD && (unsigned)ny < YD && (unsigned)nz < ZD)
      j = map[((bb*XD+nx)*YD+ny)*ZD+nz];
    jn[v][nb] = j;
  }
  __syncthreads();
  int w = t>>6, l = t&63;
  int og = l & 3, cg = l >> 2;
  int c0 = cg*8;
  float acc[8][5];
  #pragma unroll
  for (int v=0;v<8;++v)
    #pragma unroll
    for (int oo=0;oo<5;++oo) acc[v][oo]=0.f;
  for (int nb = w; nb < 27; nb += 4){
    const float* wbase = wt + (size_t)nb*NCD*CD + c0;
    float4 wreg[10];
    #pragma unroll
    for (int oo=0;oo<5;++oo){
      wreg[oo*2]   = *(const float4*)(wbase + (size_t)(og*5+oo)*CD);
      wreg[oo*2+1] = *(const float4*)(wbase + (size_t)(og*5+oo)*CD + 4);
    }
    #pragma unroll
    for (int v=0; v<8; ++v){
      int j = jn[v][nb];
      if (j < 0) continue;
      const float4* y4 = (const float4*)(yb + (size_t)j*CD + c0);
      float4 ya = y4[0], ybb = y4[1];
      #pragma unroll
      for (int oo=0;oo<5;++oo){
        float4 wa = wreg[oo*2], wb = wreg[oo*2+1];
        acc[v][oo] += ya.x*wa.x + ya.y*wa.y + ya.z*wa.z + ya.w*wa.w
                    + ybb.x*wb.x + ybb.y*wb.y + ybb.z*wb.z + ybb.w*wb.w;
      }
    }
  }
  #pragma unroll
  for (int v=0;v<8;++v)
    #pragma unroll
    for (int oo=0;oo<5;++oo){
      float s = acc[v][oo];
      s += __shfl_xor(s, 4, 64);
      s += __shfl_xor(s, 8, 64);
      s += __shfl_xor(s, 16, 64);
      s += __shfl_xor(s, 32, 64);
      if (cg == 0) partial[w][v][og*5+oo] = s;
    }
  __syncthreads();
  if (t < 160){
    int v = t/20, o = t - v*20;
    float s = partial[0][v][o]+partial[1][v][o]+partial[2][v][o]+partial[3][v][o]
            + A[OF_SEGB+o];
    if (*flag) ((ushort_t*)outv)[(size_t)(p0+v)*NCD + o] = f2bf(s);
    else       ((float*)outv)[(size_t)(p0+v)*NCD + o]   = s;
  }
}

// ---------------- launch ----------------
extern "C" void kernel_launch(void* const* d_in, const int* in_sizes, int n_in,
                              void* d_out, int out_size, void* d_ws, size_t ws_size,
                              hipStream_t stream) {
  const int* idx = (const int*)d_in[0];

  char* w = (char*)d_ws;
  size_t off = 0;
  #define ALLOC(name, type, count) \
    type* name = (type*)(w + off); off += (((size_t)(count)*sizeof(type)) + 255) & ~(size_t)255;
  ALLOC(flag,   int,   64)
  ALLOC(arena,  float, ARENA_N)
  ALLOC(wt,     float, 27*NCD*CD)
  ALLOC(map,    int,   MAPN)
  ALLOC(afold,  float, 192)
  ALLOC(scfold, float, 64)
  ALLOC(t1T,    float, CD*NSV)
  ALLOC(kb,     float, NSV*CD)
  ALLOC(vbuf,   float, NSV*CD)
  ALLOC(qb,     float, NVOX*CD)
  ALLOC(yb,     float, NVOX*CD)
  #undef ALLOC
  (void)off; (void)ws_size; (void)n_in; (void)in_sizes; (void)out_size;

  SrcPtrs sp;
  for (int i=0;i<25;++i) sp.p[i] = d_in[i+1];

  kprep   <<<512, 512, 0, stream>>>(sp, idx, flag, arena, wt, map, afold, scfold, qb, t1T);
  k6_fused<<<NSV*2, 256, 0, stream>>>(t1T, arena, idx, map, kb, vbuf);
  k9_attn <<<NVOX/4, 256, 0, stream>>>(arena, idx, afold, scfold, kb, vbuf, qb, yb);
  k10_conv<<<NVOX/8, 256, 0, stream>>>(idx, map, yb, arena, wt, flag, d_out);
}

// Round 11
// 207.238 us; speedup vs baseline: 1.1718x; 1.1718x over previous
//
#include <hip/hip_runtime.h>

typedef unsigned short ushort_t;

#define NVOX 4096
#define NSV  256
#define XD   128
#define YD   128
#define ZD   16
#define CD   128
#define NCD  20
#define HD   8
#define DHD  16
#define MAPN 524288
#define EPSF 1e-5f

// ---- fp32 arena offsets (floats) ----
#define OF_FEAT 0
#define OF_CW1  524288
#define OF_CB1  540672
#define OF_CG1  540800
#define OF_CBE1 540928
#define OF_CW2  541056
#define OF_CB2  557440
#define OF_PW1  557568
#define OF_PB1  557760
#define OF_PG1  557824
#define OF_PBE1 557888
#define OF_PW2  557952
#define OF_PB2  558016
#define OF_WQ   558080
#define OF_BQ   574464
#define OF_WK   574592
#define OF_BK   590976
#define OF_WV   591104
#define OF_BV   607488
#define OF_WO   607616
#define OF_BO   624000
#define OF_LNG  624128
#define OF_LNB  624256
#define OF_SEGW 624384
#define OF_SEGB 693504
#define ARENA_N 693568
#define TOTCVT  624341   /* segw excluded (transposed separately) */

__device__ __forceinline__ float bf2f(const ushort_t* p){
  return __uint_as_float(((unsigned)(*p)) << 16);
}
__device__ __forceinline__ ushort_t f2bf(float f){
  unsigned u = __float_as_uint(f);
  u += 0x7fffu + ((u >> 16) & 1u);
  return (ushort_t)(u >> 16);
}
__device__ __forceinline__ float unlo(unsigned u){ return __uint_as_float(u << 16); }
__device__ __forceinline__ float unhi(unsigned u){ return __uint_as_float(u & 0xffff0000u); }

struct SrcPtrs { const void* p[25]; };

__device__ const int g_cnt[25] = {524288,16384,128,128,128,16384,128,192,64,64,64,64,1,
                                  16384,128,16384,128,16384,128,16384,128,128,128,0,20};
__device__ const int g_off[25] = {OF_FEAT,OF_CW1,OF_CB1,OF_CG1,OF_CBE1,OF_CW2,OF_CB2,
                                  OF_PW1,OF_PB1,OF_PG1,OF_PBE1,OF_PW2,OF_PB2,
                                  OF_WQ,OF_BQ,OF_WK,OF_BK,OF_WV,OF_BV,OF_WO,OF_BO,
                                  OF_LNG,OF_LNB,OF_SEGW,OF_SEGB};

__device__ __forceinline__ float ldi(const void* p, int off, int fl){
  return fl ? bf2f((const ushort_t*)p + off) : ((const float*)p)[off];
}

struct SPREP {
  float frows[16][CD];     // 8 KB
  float qpart[2][16][CD];  // 16 KB
  float part[8][CD];       // 4 KB
  float cfs[CD];           // 0.5 KB
  float gpart[8][CD];      // 4 KB
};
union __align__(16) UPREP { SPREP sv; int smom[18]; };

// ========== KPREP (512 threads) ==========
__global__ __launch_bounds__(512) void kprep(SrcPtrs sp, const int* idx, int* flag,
    float* arena, float* wt, int* map, float* afold_g, float* scfold_g,
    float* qb, float* t1T)
{
  __shared__ UPREP sm;
  __shared__ int sm_flag;
  int t = threadIdx.x, b = blockIdx.x;
  if (t < 64){
    const ushort_t* f16 = (const ushort_t*)sp.p[0];
    unsigned u = f16[2*t];
    int e = (u >> 7) & 0xFF;
    int sane = (u == 0 || (e >= 90 && e <= 150)) ? 1 : 0;
    unsigned long long bl = __ballot(sane);
    if (t == 0) sm_flag = (__popcll(bl) >= 48) ? 1 : 0;
  }
  __syncthreads();
  const int fl = sm_flag;

  if (b < 255){
    int gid = b*512 + t;
    const int GS = 255*512;
    if (gid == 0) *flag = fl;
    for (int k=gid; k<MAPN; k+=GS) map[k] = -1;
    for (int el=gid; el<TOTCVT; el+=GS){
      int s=0, rem=el;
      while (rem >= g_cnt[s]){ rem -= g_cnt[s]; ++s; }
      arena[g_off[s]+rem] = ldi(sp.p[s], rem, fl);
    }
    for (int k=gid; k<27*NCD*CD; k+=GS){
      int nb = k/(NCD*CD); int rem = k - nb*(NCD*CD); int o = rem/CD, i = rem - o*CD;
      wt[k] = ldi(sp.p[23], nb*(CD*NCD) + i*NCD + o, fl);
    }
  } else if (b < 511){
    int sv = b - 255;
    int rb = sv*16;
    if (fl){
      const uint2* fsrc = (const uint2*)((const ushort_t*)sp.p[0] + (size_t)rb*CD);
      uint2 u = fsrc[t];
      float* dst = &sm.sv.frows[t>>5][(t&31)*4];
      dst[0]=unlo(u.x); dst[1]=unhi(u.x); dst[2]=unlo(u.y); dst[3]=unhi(u.y);
    } else {
      const float4* fsrc = (const float4*)((const float*)sp.p[0] + (size_t)rb*CD);
      ((float4*)sm.sv.frows)[t] = fsrc[t];
    }
    __syncthreads();
    // ---- q-proj: thread = (c8:16, row:16, khalf:2)
    {
      int c8 = (t&15)*8, r = (t>>4)&15, kh = t>>8;
      int i0 = kh*64;
      float acc[8] = {0.f,0.f,0.f,0.f,0.f,0.f,0.f,0.f};
      if (fl){
        const ushort_t* wqp = (const ushort_t*)sp.p[13];
        #pragma unroll 4
        for (int i=i0; i<i0+64; ++i){
          uint4 w4 = *(const uint4*)(wqp + (size_t)i*CD + c8);
          float fr = sm.sv.frows[r][i];
          acc[0] += unlo(w4.x)*fr; acc[1] += unhi(w4.x)*fr;
          acc[2] += unlo(w4.y)*fr; acc[3] += unhi(w4.y)*fr;
          acc[4] += unlo(w4.z)*fr; acc[5] += unhi(w4.z)*fr;
          acc[6] += unlo(w4.w)*fr; acc[7] += unhi(w4.w)*fr;
        }
      } else {
        const float* wqp = (const float*)sp.p[13];
        #pragma unroll 4
        for (int i=i0; i<i0+64; ++i){
          float4 wa = *(const float4*)(wqp + (size_t)i*CD + c8);
          float4 wb = *(const float4*)(wqp + (size_t)i*CD + c8 + 4);
          float fr = sm.sv.frows[r][i];
          acc[0]+=wa.x*fr; acc[1]+=wa.y*fr; acc[2]+=wa.z*fr; acc[3]+=wa.w*fr;
          acc[4]+=wb.x*fr; acc[5]+=wb.y*fr; acc[6]+=wb.z*fr; acc[7]+=wb.w*fr;
        }
      }
      #pragma unroll
      for (int j=0;j<8;++j) sm.sv.qpart[kh][r][c8+j] = acc[j];
    }
    __syncthreads();
    for (int e = t; e < 16*CD; e += 512){
      int r = e>>7, c = e&127;
      qb[(size_t)(rb+r)*CD + c] = sm.sv.qpart[0][r][c] + sm.sv.qpart[1][r][c]
                                + ldi(sp.p[14], c, fl);
    }
    // ---- segment softmax-sum: 8 waves x 2 rows
    {
      int w = t>>6, l = t&63;
      float a0 = 0.f, a1 = 0.f;
      #pragma unroll
      for (int k=0;k<2;++k){
        int r = w*2 + k;
        float f0 = sm.sv.frows[r][l];
        float f1 = sm.sv.frows[r][l+64];
        float m = fmaxf(f0,f1);
        #pragma unroll
        for (int o=32;o;o>>=1) m = fmaxf(m, __shfl_xor(m,o,64));
        float e0 = __expf(f0-m), e1 = __expf(f1-m);
        float ssum = e0+e1;
        #pragma unroll
        for (int o=32;o;o>>=1) ssum += __shfl_xor(ssum,o,64);
        float inv = 1.f/ssum;
        a0 += e0*inv; a1 += e1*inv;
      }
      sm.sv.part[w][l] = a0; sm.sv.part[w][l+64] = a1;
    }
    __syncthreads();
    if (t < CD){
      float s = 0.f;
      #pragma unroll
      for (int w=0;w<8;++w) s += sm.sv.part[w][t];
      sm.sv.cfs[t] = s;
    }
    __syncthreads();
    // ---- GEMV1: thread = (c2:64, kg:8)
    {
      int c2 = (t&63)*2, kg = t>>6;
      int i0 = kg*16;
      float a0 = 0.f, a1 = 0.f;
      if (fl){
        const ushort_t* W = (const ushort_t*)sp.p[1];
        #pragma unroll 4
        for (int i=i0; i<i0+16; ++i){
          unsigned w = *(const unsigned*)(W + (size_t)i*CD + c2);
          float cfv = sm.sv.cfs[i];
          a0 += unlo(w)*cfv; a1 += unhi(w)*cfv;
        }
      } else {
        const float* W = (const float*)sp.p[1];
        #pragma unroll 4
        for (int i=i0; i<i0+16; ++i){
          float2 w = *(const float2*)(W + (size_t)i*CD + c2);
          float cfv = sm.sv.cfs[i];
          a0 += w.x*cfv; a1 += w.y*cfv;
        }
      }
      sm.sv.gpart[kg][c2] = a0; sm.sv.gpart[kg][c2+1] = a1;
    }
    __syncthreads();
    if (t < CD){
      float s = 0.f;
      #pragma unroll
      for (int kg=0;kg<8;++kg) s += sm.sv.gpart[kg][t];
      t1T[(size_t)t*NSV + sv] = s + ldi(sp.p[2], t, fl);
    }
  } else {
    // ---- b == 511: moments + BN fold (wave-reduced, no per-lane LDS atomic storms)
    if (t < 18) sm.smom[t] = 0;
    __syncthreads();
    {
      // voxel moments
      int sacc[9] = {0,0,0,0,0,0,0,0,0};
      for (int v = t; v < NVOX; v += 512){
        int4 q = ((const int4*)idx)[v];
        sacc[0]+=q.y; sacc[1]+=q.z; sacc[2]+=q.w;
        sacc[3]+=q.y*q.y; sacc[4]+=q.z*q.z; sacc[5]+=q.w*q.w;
        sacc[6]+=q.y*q.z; sacc[7]+=q.y*q.w; sacc[8]+=q.z*q.w;
      }
      // supervoxel (cell) moments
      int um[9] = {0,0,0,0,0,0,0,0,0};
      if (t < 256){
        int4 q = ((const int4*)idx)[t*16];
        int gx=q.y>>2, gy=q.z>>2, gz=q.w>>2;
        um[0]=gx; um[1]=gy; um[2]=gz;
        um[3]=gx*gx; um[4]=gy*gy; um[5]=gz*gz;
        um[6]=gx*gy; um[7]=gx*gz; um[8]=gy*gz;
      }
      // 64-lane shuffle tree per moment, one atomic per wave per moment
      int lane = t & 63;
      #pragma unroll
      for (int i=0;i<9;++i){
        int s = sacc[i];
        int u = um[i];
        #pragma unroll
        for (int o=32;o;o>>=1){
          s += __shfl_xor(s, o, 64);
          u += __shfl_xor(u, o, 64);
        }
        if (lane == 0){
          if (s) atomicAdd(&sm.smom[9+i], s);
          if (u) atomicAdd(&sm.smom[i], u);
        }
      }
    }
    __syncthreads();
    if (t < 64){
      int* smom = sm.smom;
      double U1[3]={(double)smom[0],(double)smom[1],(double)smom[2]};
      double S1[3]={(double)smom[9],(double)smom[10],(double)smom[11]};
      double Uxx[3][3], Sxx[3][3];
      Uxx[0][0]=smom[3]; Uxx[1][1]=smom[4]; Uxx[2][2]=smom[5];
      Uxx[0][1]=Uxx[1][0]=smom[6]; Uxx[0][2]=Uxx[2][0]=smom[7]; Uxx[1][2]=Uxx[2][1]=smom[8];
      Sxx[0][0]=smom[12]; Sxx[1][1]=smom[13]; Sxx[2][2]=smom[14];
      Sxx[0][1]=Sxx[1][0]=smom[15]; Sxx[0][2]=Sxx[2][0]=smom[16]; Sxx[1][2]=Sxx[2][1]=smom[17];
      double M1[3], M2[3][3];
      for (int a=0;a<3;++a) M1[a] = 256.0*S1[a] - 4096.0*U1[a];
      for (int a=0;a<3;++a)
        for (int b2=0;b2<3;++b2)
          M2[a][b2] = 256.0*Sxx[a][b2] - S1[a]*U1[b2] - S1[b2]*U1[a] + 4096.0*Uxx[a][b2];
      double wv_[3]={(double)ldi(sp.p[7],t,fl),(double)ldi(sp.p[7],64+t,fl),(double)ldi(sp.p[7],128+t,fl)};
      double bj=(double)ldi(sp.p[8],t,fl), gj=(double)ldi(sp.p[9],t,fl), bej=(double)ldi(sp.p[10],t,fl);
      double Mw=0.0, wMw=0.0;
      for (int a=0;a<3;++a){
        Mw += M1[a]*wv_[a];
        for (int b2=0;b2<3;++b2) wMw += wv_[a]*M2[a][b2]*wv_[b2];
      }
      const double NM = 1048576.0;
      double mean = Mw/NM + bj;
      double Ey2  = wMw/NM + 2.0*bj*Mw/NM + bj*bj;
      double var  = Ey2 - mean*mean;
      double scale = gj / sqrt(var + 1e-5);
      afold_g[t]      = (float)(wv_[0]*scale);
      afold_g[64+t]   = (float)(wv_[1]*scale);
      afold_g[128+t]  = (float)(wv_[2]*scale);
      scfold_g[t]     = (float)(bj*scale + bej - mean*scale);
    }
  }
}

// ========== K6: 512 blocks (role = b>>8: 0=k, 1=v); map scatter on role 0 ==========
__global__ __launch_bounds__(256) void k6_fused(const float* t1T, const float* A,
    const int* idx, int* map, float* kb, float* vb){
  __shared__ float row[CD];
  __shared__ float cpar[2][CD];
  __shared__ float hrow[CD];
  int t = threadIdx.x;
  int role = blockIdx.x >> 8, s = blockIdx.x & 255;
  if (role == 0 && t >= 128 && t < 144){
    int v = s*16 + (t-128);
    int4 q = ((const int4*)idx)[v];
    map[((q.x*XD + q.y)*YD + q.z)*ZD + q.w] = v;
  }
  if (t < CD){
    const float4* col = (const float4*)(t1T + (size_t)t*NSV);
    float sum=0.f, sq=0.f;
    #pragma unroll 8
    for (int i=0;i<NSV/4;++i){
      float4 v = col[i];
      sum += v.x+v.y+v.z+v.w;
      sq  += v.x*v.x+v.y*v.y+v.z*v.z+v.w*v.w;
    }
    float mean = sum*(1.f/256.f);
    float var  = sq*(1.f/256.f) - mean*mean;
    float scv = A[OF_CG1+t]*rsqrtf(var+EPSF);
    float shv = A[OF_CBE1+t] - mean*scv;
    row[t] = fmaxf(t1T[(size_t)t*NSV + s]*scv + shv, 0.f);
  }
  __syncthreads();
  int c = t&127, half = t>>7;
  {
    const float* W = A + OF_CW2;
    float acc = 0.f;
    #pragma unroll 8
    for (int i=half*64;i<half*64+64;++i) acc += row[i]*W[i*CD+c];
    cpar[half][c] = acc;
  }
  __syncthreads();
  if (t < CD) hrow[t] = cpar[0][t]+cpar[1][t]+A[OF_CB2+t];
  __syncthreads();
  // proj: split K over thread halves
  {
    const float* W = role ? (A+OF_WV) : (A+OF_WK);
    float acc = 0.f;
    #pragma unroll 8
    for (int i=half*64;i<half*64+64;++i) acc += hrow[i]*W[i*CD+c];
    cpar[half][c] = acc;
  }
  __syncthreads();
  if (t < CD){
    float v = cpar[0][t]+cpar[1][t] + (role ? A[OF_BV+t] : A[OF_BK+t]);
    if (role) vb[(size_t)s*CD+t] = v; else kb[(size_t)s*CD+t] = v;
  }
}

// ========== K9: pbias + attention + wo + residual + LN (4q/block, fp32 probs)
__global__ __launch_bounds__(256) void k9_attn(
    const float* A, const int* idx, const float* afold_g, const float* scfold_g,
    const float* kb, const float* vb, const float* qb, float* yb)
{
  __shared__ __align__(16) float q4s[4][CD];       // 2 KB
  __shared__ __align__(16) float scf[NSV][36];     // 36.9 KB fp32 probs [s][h*4+g]
  __shared__ __align__(16) float ctxT[CD*4];       // 2 KB
  __shared__ float cpart[2][4][CD];                // 4 KB
  __shared__ __align__(16) float e4T[64][4];       // 1 KB
  __shared__ float saf[3][64];
  __shared__ float ssc[64];
  __shared__ float w2s[64];
  __shared__ float rinv[32];
  int t = threadIdx.x;
  int n0 = blockIdx.x*4;
  if (t < 128) ((float4*)q4s)[t] = ((const float4*)(qb + (size_t)n0*CD))[t];
  if (t < 64){
    saf[0][t] = afold_g[t]; saf[1][t] = afold_g[64+t]; saf[2][t] = afold_g[128+t];
    ssc[t] = scfold_g[t]; w2s[t] = A[OF_PW2+t];
  }
  __syncthreads();
  {
    int g = t>>6, j = t&63;
    float xv = (float)idx[4*(n0+g)+1];
    float yv = (float)idx[4*(n0+g)+2];
    float zv = (float)idx[4*(n0+g)+3];
    e4T[j][g] = saf[0][j]*xv + saf[1][j]*yv + saf[2][j]*zv;
  }
  __syncthreads();
  // pbias + scores + exp for supervoxel s = t
  {
    int4 q0 = ((const int4*)idx)[t*16];
    float uxf = (float)(q0.y>>2), uyf = (float)(q0.z>>2), uzf = (float)(q0.w>>2);
    float pbv[4];
    float pb2v = A[OF_PB2];
    #pragma unroll
    for (int g=0;g<4;++g) pbv[g] = pb2v;
    #pragma unroll 2
    for (int j=0;j<64;++j){
      float dj = ssc[j] - (saf[0][j]*uxf + saf[1][j]*uyf + saf[2][j]*uzf);
      float wj = w2s[j];
      float4 ea = *(const float4*)&e4T[j][0];
      pbv[0] += fmaxf(ea.x+dj,0.f)*wj; pbv[1] += fmaxf(ea.y+dj,0.f)*wj;
      pbv[2] += fmaxf(ea.z+dj,0.f)*wj; pbv[3] += fmaxf(ea.w+dj,0.f)*wj;
    }
    const float4* krow = (const float4*)(kb + (size_t)t*CD);
    float4 kc0 = krow[0], kc1 = krow[1], kc2 = krow[2], kc3 = krow[3];
    for (int h=0;h<HD;++h){
      int hn = (h+1)&7;
      float4 kn0 = krow[hn*4+0], kn1 = krow[hn*4+1];
      float4 kn2 = krow[hn*4+2], kn3 = krow[hn*4+3];
      float p[4];
      #pragma unroll
      for (int g=0;g<4;++g){
        const float* qg = &q4s[g][h*DHD];
        float dot = qg[0]*kc0.x + qg[1]*kc0.y + qg[2]*kc0.z + qg[3]*kc0.w
                  + qg[4]*kc1.x + qg[5]*kc1.y + qg[6]*kc1.z + qg[7]*kc1.w
                  + qg[8]*kc2.x + qg[9]*kc2.y + qg[10]*kc2.z + qg[11]*kc2.w
                  + qg[12]*kc3.x + qg[13]*kc3.y + qg[14]*kc3.z + qg[15]*kc3.w;
        p[g] = __expf(dot*0.25f + pbv[g]);
      }
      *(float4*)&scf[t][h*4] = make_float4(p[0],p[1],p[2],p[3]);
      kc0 = kn0; kc1 = kn1; kc2 = kn2; kc3 = kn3;
    }
  }
  __syncthreads();
  // denominators: wave g handles query g, all 8 heads
  {
    int g = t>>6, lane = t&63;
    for (int h=0;h<HD;++h){
      int col = h*4 + g;
      float s0 = scf[lane][col] + scf[lane+64][col] + scf[lane+128][col] + scf[lane+192][col];
      #pragma unroll
      for (int o=32;o;o>>=1) s0 += __shfl_xor(s0,o,64);
      if (lane==0) rinv[g*8+h] = 1.f/s0;
    }
  }
  __syncthreads();
  // PV: float4 LDS broadcast + 4-wide v-load unroll
  {
    int half=t>>7, c=t&127, h=c>>4;
    const float* vcol = vb + c;
    float acc[4]={0.f,0.f,0.f,0.f};
    #pragma unroll 4
    for (int s0=half*128; s0<half*128+128; s0+=4){
      float v0=vcol[(s0+0)*CD], v1=vcol[(s0+1)*CD], v2=vcol[(s0+2)*CD], v3=vcol[(s0+3)*CD];
      float4 p0 = *(const float4*)&scf[s0+0][h*4];
      float4 p1 = *(const float4*)&scf[s0+1][h*4];
      float4 p2 = *(const float4*)&scf[s0+2][h*4];
      float4 p3 = *(const float4*)&scf[s0+3][h*4];
      acc[0] += p0.x*v0 + p1.x*v1 + p2.x*v2 + p3.x*v3;
      acc[1] += p0.y*v0 + p1.y*v1 + p2.y*v2 + p3.y*v3;
      acc[2] += p0.z*v0 + p1.z*v1 + p2.z*v2 + p3.z*v3;
      acc[3] += p0.w*v0 + p1.w*v1 + p2.w*v2 + p3.w*v3;
    }
    #pragma unroll
    for (int g=0;g<4;++g) cpart[half][g][c]=acc[g];
  }
  __syncthreads();
  if (t < CD){
    int h = t>>4;
    #pragma unroll
    for (int g=0;g<4;++g)
      ctxT[t*4+g] = (cpart[0][g][t]+cpart[1][g][t])*rinv[g*8+h];
  }
  __syncthreads();
  // wo
  {
    int half=t>>7, c=t&127;
    const float* wo = A + OF_WO;
    float acc[4]={0.f,0.f,0.f,0.f};
    #pragma unroll 4
    for (int i=half*64;i<half*64+64;++i){
      float wv = wo[i*CD+c];
      float4 r = *(const float4*)&ctxT[i*4];
      acc[0]+=r.x*wv; acc[1]+=r.y*wv; acc[2]+=r.z*wv; acc[3]+=r.w*wv;
    }
    #pragma unroll
    for (int g=0;g<4;++g) cpart[half][g][c]=acc[g];
  }
  __syncthreads();
  if (t < CD){
    float bov = A[OF_BO+t];
    #pragma unroll
    for (int g=0;g<4;++g)
      ctxT[t*4+g] = cpart[0][g][t]+cpart[1][g][t] + bov
                  + A[OF_FEAT + (size_t)(n0+g)*CD + t];
  }
  __syncthreads();
  // LayerNorm: wave g handles row g
  {
    int g = t>>6, lane = t&63;
    float x0 = ctxT[lane*4+g], x1 = ctxT[(lane+64)*4+g];
    float s1 = x0+x1, s2 = x0*x0+x1*x1;
    #pragma unroll
    for (int o=32;o;o>>=1){ s1 += __shfl_xor(s1,o,64); s2 += __shfl_xor(s2,o,64); }
    float mean = s1*(1.f/128.f);
    float var  = s2*(1.f/128.f) - mean*mean;
    float rs = rsqrtf(var + EPSF);
    yb[(size_t)(n0+g)*CD + lane]    = (x0-mean)*rs*A[OF_LNG+lane]    + A[OF_LNB+lane];
    yb[(size_t)(n0+g)*CD + lane+64] = (x1-mean)*rs*A[OF_LNG+lane+64] + A[OF_LNB+lane+64];
  }
}

// ========== K10: SubMConv3d, 8 voxels/block (512 blocks), weights hoisted ==========
__global__ __launch_bounds__(256) void k10_conv(const int* idx, const int* map,
    const float* yb, const float* A, const float* wt, const int* flag, void* outv)
{
  __shared__ int sco4[8][4];
  __shared__ int jn[8][27];
  __shared__ float partial[4][8][NCD];
  int t = threadIdx.x;
  int p0 = blockIdx.x*8;
  if (t < 32) ((int*)sco4)[t] = idx[4*p0 + t];
  __syncthreads();
  if (t < 216){
    int v = t/27, nb = t - v*27;
    int kd = nb/9, kh = (nb/3)%3, kw = nb%3;
    int bb = sco4[v][0];
    int nx = sco4[v][1]+kd-1, ny = sco4[v][2]+kh-1, nz = sco4[v][3]+kw-1;
    int j = -1;
    if ((unsigned)nx < XD && (unsigned)ny < YD && (unsigned)nz < ZD)
      j = map[((bb*XD+nx)*YD+ny)*ZD+nz];
    jn[v][nb] = j;
  }
  __syncthreads();
  int w = t>>6, l = t&63;
  int og = l & 3, cg = l >> 2;
  int c0 = cg*8;
  float acc[8][5];
  #pragma unroll
  for (int v=0;v<8;++v)
    #pragma unroll
    for (int oo=0;oo<5;++oo) acc[v][oo]=0.f;
  for (int nb = w; nb < 27; nb += 4){
    const float* wbase = wt + (size_t)nb*NCD*CD + c0;
    float4 wreg[10];
    #pragma unroll
    for (int oo=0;oo<5;++oo){
      wreg[oo*2]   = *(const float4*)(wbase + (size_t)(og*5+oo)*CD);
      wreg[oo*2+1] = *(const float4*)(wbase + (size_t)(og*5+oo)*CD + 4);
    }
    #pragma unroll
    for (int v=0; v<8; ++v){
      int j = jn[v][nb];
      if (j < 0) continue;
      const float4* y4 = (const float4*)(yb + (size_t)j*CD + c0);
      float4 ya = y4[0], ybb = y4[1];
      #pragma unroll
      for (int oo=0;oo<5;++oo){
        float4 wa = wreg[oo*2], wb = wreg[oo*2+1];
        acc[v][oo] += ya.x*wa.x + ya.y*wa.y + ya.z*wa.z + ya.w*wa.w
                    + ybb.x*wb.x + ybb.y*wb.y + ybb.z*wb.z + ybb.w*wb.w;
      }
    }
  }
  #pragma unroll
  for (int v=0;v<8;++v)
    #pragma unroll
    for (int oo=0;oo<5;++oo){
      float s = acc[v][oo];
      s += __shfl_xor(s, 4, 64);
      s += __shfl_xor(s, 8, 64);
      s += __shfl_xor(s, 16, 64);
      s += __shfl_xor(s, 32, 64);
      if (cg == 0) partial[w][v][og*5+oo] = s;
    }
  __syncthreads();
  if (t < 160){
    int v = t/20, o = t - v*20;
    float s = partial[0][v][o]+partial[1][v][o]+partial[2][v][o]+partial[3][v][o]
            + A[OF_SEGB+o];
    if (*flag) ((ushort_t*)outv)[(size_t)(p0+v)*NCD + o] = f2bf(s);
    else       ((float*)outv)[(size_t)(p0+v)*NCD + o]   = s;
  }
}

// ---------------- launch ----------------
extern "C" void kernel_launch(void* const* d_in, const int* in_sizes, int n_in,
                              void* d_out, int out_size, void* d_ws, size_t ws_size,
                              hipStream_t stream) {
  const int* idx = (const int*)d_in[0];

  char* w = (char*)d_ws;
  size_t off = 0;
  #define ALLOC(name, type, count) \
    type* name = (type*)(w + off); off += (((size_t)(count)*sizeof(type)) + 255) & ~(size_t)255;
  ALLOC(flag,   int,   64)
  ALLOC(arena,  float, ARENA_N)
  ALLOC(wt,     float, 27*NCD*CD)
  ALLOC(map,    int,   MAPN)
  ALLOC(afold,  float, 192)
  ALLOC(scfold, float, 64)
  ALLOC(t1T,    float, CD*NSV)
  ALLOC(kb,     float, NSV*CD)
  ALLOC(vbuf,   float, NSV*CD)
  ALLOC(qb,     float, NVOX*CD)
  ALLOC(yb,     float, NVOX*CD)
  #undef ALLOC
  (void)off; (void)ws_size; (void)n_in; (void)in_sizes; (void)out_size;

  SrcPtrs sp;
  for (int i=0;i<25;++i) sp.p[i] = d_in[i+1];

  kprep   <<<512, 512, 0, stream>>>(sp, idx, flag, arena, wt, map, afold, scfold, qb, t1T);
  k6_fused<<<NSV*2, 256, 0, stream>>>(t1T, arena, idx, map, kb, vbuf);
  k9_attn <<<NVOX/4, 256, 0, stream>>>(arena, idx, afold, scfold, kb, vbuf, qb, yb);
  k10_conv<<<NVOX/8, 256, 0, stream>>>(idx, map, yb, arena, wt, flag, d_out);
}